// Round 3
// baseline (1695.441 us; speedup 1.0000x reference)
//
#include <hip/hip_runtime.h>
#include <hip/hip_bf16.h>
#include <stdint.h>

// fSRN: fused SIREN + 3 forward-mode tangent streams, MFMA engine, v3.
// WG = 256 threads (4 waves), 32 points. Activation matrix A = 128 rows
// (4 streams x 32 points) x 128 features, bf16 in LDS with XOR-chunk swizzle.
//   rows  0..31  primal h     rows 32..63  dh_x
//   rows 64..95  dh_y         rows 96..127 dh_z
// Wave (wm = wave>>1, wn = wave&1) computes output tile
//   rows [wm*64, +64) x cols [wn*64, +64):  4mt x 4nt x 4kk mfma 16x16x32.
// 76.4 KB LDS -> 2 WGs/CU co-resident (decoupled barrier domains).

#define OMEGA_C 30.0f

constexpr int NPTS = 131072;
constexpr int FDIM = 128;
constexpr int NBLK = 3;
constexpr int P_WG = 32;
constexpr int NTHR = 256;   // 4 waves

typedef short bf16x8 __attribute__((ext_vector_type(8)));
typedef float f32x4  __attribute__((ext_vector_type(4)));

__device__ __forceinline__ uint32_t bfbits(float f) {
    union { float f; uint32_t u; } x; x.f = f;
    uint32_t u = x.u;
    return (u + 0x7FFFu + ((u >> 16) & 1u)) >> 16;   // RNE
}
__device__ __forceinline__ float u16tof(uint16_t h) {
    union { uint32_t u; float f; } x; x.u = ((uint32_t)h) << 16; return x.f;
}

// swizzled byte offset into a [rows][128] bf16 tile with 256 B rows:
// 16B chunk index is XORed with (row & 15)  -> conflict-free b128 reads
// (2-way only) AND spread scalar b16 stores.
__device__ __forceinline__ int swz(int row, int col) {
    const int b = col << 1;
    return (row << 8) + ((((b >> 4) ^ (row & 15)) << 4) | (b & 15));
}

__global__ __launch_bounds__(NTHR, 2) void fsrn_kernel(
    const float* __restrict__ coords,
    const float* __restrict__ first_w,
    const float* __restrict__ first_b,
    const float* __restrict__ res_w1,
    const float* __restrict__ res_b1,
    const float* __restrict__ res_w2,
    const float* __restrict__ res_b2,
    const float* __restrict__ final_w,
    float* __restrict__ out)
{
    __shared__ __align__(16) uint8_t A8[128 * 256];   // 32 KiB activations (bf16, swizzled)
    __shared__ __align__(16) uint8_t W8[128 * 256];   // 32 KiB weights    (bf16, swizzled)
    __shared__ __align__(16) uint8_t C8[32 * 256];    //  8 KiB OMEGA*cos  (bf16, swizzled)
    __shared__ float xyz[P_WG * 3];                   // 384 B
    __shared__ float outp[3][2][P_WG][3];             // 2304 B

    const int tid  = threadIdx.x;
    const int wave = tid >> 6;
    const int lane = tid & 63;
    const int l15  = lane & 15;
    const int lq   = lane >> 4;            // 0..3
    const int wm   = wave >> 1;            // row-block (0: primal+dx, 1: dy+dz)
    const int wn   = wave & 1;             // col-half
    const int rowbase = wm * 64;
    const int colbase = wn * 64;
    const int pt0  = blockIdx.x * P_WG;

    float mst[4][4][4];    // master state (h / dh), fp32: [mt][nt][j]
    f32x4 acc[4][4];       // MFMA accumulators [mt][nt]

    // ---- stage coords ----
    if (tid < P_WG * 3) xyz[tid] = coords[pt0 * 3 + tid];

    // stage weights into LDS (bf16, scale folded, swizzled chunks)
    auto stageW = [&](const float* __restrict__ src, float scale) {
        #pragma unroll
        for (int i = 0; i < 8; ++i) {
            const int g   = tid + (i << 8);        // chunk id 0..2047
            const int row = g >> 4, c = g & 15;
            const float4 v0 = *reinterpret_cast<const float4*>(src + (g << 3));
            const float4 v1 = *reinterpret_cast<const float4*>(src + (g << 3) + 4);
            uint4 w;
            w.x = bfbits(scale*v0.x) | (bfbits(scale*v0.y) << 16);
            w.y = bfbits(scale*v0.z) | (bfbits(scale*v0.w) << 16);
            w.z = bfbits(scale*v1.x) | (bfbits(scale*v1.y) << 16);
            w.w = bfbits(scale*v1.z) | (bfbits(scale*v1.w) << 16);
            *reinterpret_cast<uint4*>(W8 + (row << 8) + (((c ^ (row & 15)) << 4))) = w;
        }
    };

    stageW(res_w1, 1.0f);      // block 0 layer 1 (s=1)
    __syncthreads();

    // ---- first layer: all streams in parallel ----
    #pragma unroll
    for (int mt = 0; mt < 4; ++mt) {
        const int s_mt = 2*wm + (mt >> 1);     // stream of these rows
        #pragma unroll
        for (int nt = 0; nt < 4; ++nt) {
            const int f = colbase + nt*16 + l15;
            const float w0 = first_w[f*3+0], w1 = first_w[f*3+1], w2 = first_w[f*3+2];
            const float fb = first_b[f];
            const float wk = (s_mt == 1) ? w0 : (s_mt == 2) ? w1 : w2;
            #pragma unroll
            for (int j = 0; j < 4; ++j) {
                const int p = (mt & 1)*16 + lq*4 + j;
                const float pre = OMEGA_C * (xyz[p*3]*w0 + xyz[p*3+1]*w1 + xyz[p*3+2]*w2 + fb);
                const float v = (s_mt == 0) ? __sinf(pre) : OMEGA_C * __cosf(pre) * wk;
                mst[mt][nt][j] = v;
                *reinterpret_cast<uint16_t*>(A8 + swz(rowbase + mt*16 + lq*4 + j, f))
                    = (uint16_t)bfbits(v);
            }
        }
    }
    __syncthreads();

    // MFMA GEMM: acc[mt][nt] = A[rowtile] @ W[coltile]^T
    auto gemm = [&]() {
        #pragma unroll
        for (int mt = 0; mt < 4; ++mt)
            #pragma unroll
            for (int nt = 0; nt < 4; ++nt) acc[mt][nt] = f32x4{0.f,0.f,0.f,0.f};
        #pragma unroll
        for (int kk = 0; kk < 4; ++kk) {
            bf16x8 af[4];
            #pragma unroll
            for (int mt = 0; mt < 4; ++mt)
                af[mt] = *reinterpret_cast<const bf16x8*>(
                    A8 + swz(rowbase + mt*16 + l15, kk*32 + lq*8));
            #pragma unroll
            for (int nt = 0; nt < 4; ++nt) {
                const bf16x8 wf = *reinterpret_cast<const bf16x8*>(
                    W8 + swz(colbase + nt*16 + l15, kk*32 + lq*8));
                #pragma unroll
                for (int mt = 0; mt < 4; ++mt)
                    acc[mt][nt] = __builtin_amdgcn_mfma_f32_16x16x32_bf16(af[mt], wf, acc[mt][nt], 0, 0, 0);
            }
        }
    };

    // primal rows (wm==0, mt 0..1): sin/cos, publish cos, write A
    auto do_primal = [&](const float* __restrict__ bias, bool sub2) {
        #pragma unroll
        for (int mt = 0; mt < 2; ++mt)
            #pragma unroll
            for (int nt = 0; nt < 4; ++nt) {
                const int f = colbase + nt*16 + l15;
                const float ob = OMEGA_C * bias[f];
                #pragma unroll
                for (int j = 0; j < 4; ++j) {
                    const int p = mt*16 + lq*4 + j;      // row == p for primal
                    const float pre = OMEGA_C * acc[mt][nt][j] + ob;
                    const float sv = __sinf(pre);
                    const float cv = OMEGA_C * __cosf(pre);
                    *reinterpret_cast<uint16_t*>(C8 + swz(p, f)) = (uint16_t)bfbits(cv);
                    float v;
                    if (!sub2) v = sv;
                    else { mst[mt][nt][j] += sv; v = mst[mt][nt][j]; }
                    *reinterpret_cast<uint16_t*>(A8 + swz(p, f)) = (uint16_t)bfbits(v);
                }
            }
    };

    // tangent rows: dh = cos * acc (+ residual), write A
    auto do_tangent = [&](int mt, bool sub2) {
        #pragma unroll
        for (int nt = 0; nt < 4; ++nt) {
            const int f = colbase + nt*16 + l15;
            #pragma unroll
            for (int j = 0; j < 4; ++j) {
                const int p = (mt & 1)*16 + lq*4 + j;
                const float cv = u16tof(*reinterpret_cast<const uint16_t*>(C8 + swz(p, f)));
                float v;
                if (!sub2) v = cv * acc[mt][nt][j];
                else { mst[mt][nt][j] += cv * acc[mt][nt][j]; v = mst[mt][nt][j]; }
                *reinterpret_cast<uint16_t*>(A8 + swz(rowbase + mt*16 + lq*4 + j, f))
                    = (uint16_t)bfbits(v);
            }
        }
    };

    #pragma unroll 1
    for (int b = 0; b < NBLK; ++b) {
        // ---- sub-layer 1: W = s*w1[b] ----
        gemm();
        if (wm == 0) do_primal(res_b1 + b*FDIM, false);
        __syncthreads();
        if (wm == 0) { do_tangent(2, false); do_tangent(3, false); }
        else         { do_tangent(0, false); do_tangent(1, false);
                       do_tangent(2, false); do_tangent(3, false); }
        stageW(res_w2 + b*FDIM*FDIM, 1.0f);
        __syncthreads();

        // ---- sub-layer 2: W = w2[b], residual ----
        gemm();
        if (wm == 0) do_primal(res_b2 + b*FDIM, true);
        __syncthreads();
        if (wm == 0) { do_tangent(2, true); do_tangent(3, true); }
        else         { do_tangent(0, true); do_tangent(1, true);
                       do_tangent(2, true); do_tangent(3, true); }
        if (b < NBLK-1) stageW(res_w1 + (b+1)*FDIM*FDIM, 0.5f);   // s=0.5 folded
        __syncthreads();
    }

    // ---- final: out[:,c] = signed combos of dh_k . final_w[row] ----
    auto do_final = [&](int mt) {
        const int k = 2*wm + (mt >> 1) - 1;       // tangent index 0..2
        int wrs[3]; float sgs[3];
        if (k == 0)      { wrs[0]=0; sgs[0]= 1.f; wrs[1]=3; sgs[1]=-1.f; wrs[2]=2; sgs[2]= 1.f; }
        else if (k == 1) { wrs[0]=3; sgs[0]= 1.f; wrs[1]=0; sgs[1]= 1.f; wrs[2]=1; sgs[2]=-1.f; }
        else             { wrs[0]=2; sgs[0]=-1.f; wrs[1]=1; sgs[1]= 1.f; wrs[2]=0; sgs[2]= 1.f; }
        #pragma unroll
        for (int c = 0; c < 3; ++c) {
            const int wr = wrs[c]; const float sg = sgs[c];
            float fwv[4];
            #pragma unroll
            for (int nt = 0; nt < 4; ++nt) fwv[nt] = final_w[wr*FDIM + colbase + nt*16 + l15];
            #pragma unroll
            for (int j = 0; j < 4; ++j) {
                float part = 0.0f;
                #pragma unroll
                for (int nt = 0; nt < 4; ++nt) part += mst[mt][nt][j] * fwv[nt];
                part += __shfl_xor(part, 1);
                part += __shfl_xor(part, 2);
                part += __shfl_xor(part, 4);
                part += __shfl_xor(part, 8);
                if (l15 == 0) outp[k][wn][(mt & 1)*16 + lq*4 + j][c] = sg * part;
            }
        }
    };
    if (wm == 0) { do_final(2); do_final(3); }
    else         { do_final(0); do_final(1); do_final(2); do_final(3); }
    __syncthreads();

    if (tid < P_WG * 3) {
        const int p = tid / 3, c = tid % 3;
        out[(pt0 + p)*3 + c] = outp[0][0][p][c] + outp[0][1][p][c]
                             + outp[1][0][p][c] + outp[1][1][p][c]
                             + outp[2][0][p][c] + outp[2][1][p][c];
    }
}

extern "C" void kernel_launch(void* const* d_in, const int* in_sizes, int n_in,
                              void* d_out, int out_size, void* d_ws, size_t ws_size,
                              hipStream_t stream) {
    const float* coords  = (const float*)d_in[0];
    const float* first_w = (const float*)d_in[1];
    const float* first_b = (const float*)d_in[2];
    const float* res_w1  = (const float*)d_in[3];
    const float* res_b1  = (const float*)d_in[4];
    const float* res_w2  = (const float*)d_in[5];
    const float* res_b2  = (const float*)d_in[6];
    const float* final_w = (const float*)d_in[7];
    // final_b (d_in[8]) does not influence the Jacobian -> unused.

    dim3 grid(NPTS / P_WG);   // 4096 workgroups
    fsrn_kernel<<<grid, NTHR, 0, stream>>>(coords, first_w, first_b,
                                           res_w1, res_b1, res_w2, res_b2,
                                           final_w, (float*)d_out);
}

// Round 4
// 1627.964 us; speedup vs baseline: 1.0414x; 1.0414x over previous
//
#include <hip/hip_runtime.h>
#include <hip/hip_bf16.h>
#include <stdint.h>

// fSRN: fused SIREN + 3 forward-mode tangent streams, MFMA engine, v4.
// WG = 256 threads (4 waves), 32 points. A = 128 rows (4 streams x 32 pts)
// x 128 features, bf16 in LDS, XOR-chunk swizzle. Wave (wm,wn) computes the
// 64x64 output tile rows [wm*64,+64) x cols [wn*64,+64): 4x4x4 mfma 16x16x32.
// 76.4 KB LDS -> 2 WGs/CU (two independent barrier domains per CU).
// v4: ALL register-array indices are compile-time (rule #20 — v3's lambda
// int-params demoted mst/acc to scratch: 1.8 GB HBM spill traffic).
// Primal A-writes deferred to after the post-gemm barrier (v3 race fix).

#define OMEGA_C 30.0f

constexpr int NPTS = 131072;
constexpr int FDIM = 128;
constexpr int NBLK = 3;
constexpr int P_WG = 32;
constexpr int NTHR = 256;   // 4 waves

typedef short bf16x8 __attribute__((ext_vector_type(8)));
typedef float f32x4  __attribute__((ext_vector_type(4)));

__device__ __forceinline__ uint32_t bfbits(float f) {
    union { float f; uint32_t u; } x; x.f = f;
    uint32_t u = x.u;
    return (u + 0x7FFFu + ((u >> 16) & 1u)) >> 16;   // RNE
}
__device__ __forceinline__ float u16tof(uint16_t h) {
    union { uint32_t u; float f; } x; x.u = ((uint32_t)h) << 16; return x.f;
}

// swizzled byte offset into a [rows][128] bf16 tile with 256 B rows:
// 16B chunk index XORed with (row & 15) -> aligned b128 reads stay 2-way,
// scalar b16 stores spread across banks.
__device__ __forceinline__ int swz(int row, int col) {
    const int b = col << 1;
    return (row << 8) + ((((b >> 4) ^ (row & 15)) << 4) | (b & 15));
}

__global__ __launch_bounds__(NTHR, 2) void fsrn_kernel(
    const float* __restrict__ coords,
    const float* __restrict__ first_w,
    const float* __restrict__ first_b,
    const float* __restrict__ res_w1,
    const float* __restrict__ res_b1,
    const float* __restrict__ res_w2,
    const float* __restrict__ res_b2,
    const float* __restrict__ final_w,
    float* __restrict__ out)
{
    __shared__ __align__(16) uint8_t A8[128 * 256];   // 32 KiB activations
    __shared__ __align__(16) uint8_t W8[128 * 256];   // 32 KiB weights
    __shared__ __align__(16) uint8_t C8[32 * 256];    //  8 KiB OMEGA*cos
    __shared__ float xyz[P_WG * 3];
    __shared__ float outp[3][2][P_WG][3];

    const int tid  = threadIdx.x;
    const int wave = tid >> 6;
    const int lane = tid & 63;
    const int l15  = lane & 15;
    const int lq   = lane >> 4;            // 0..3
    const int wm   = wave >> 1;            // 0: rows 0..63 (primal+dx), 1: rows 64..127 (dy+dz)
    const int wn   = wave & 1;             // col-half
    const int rowbase = wm * 64;
    const int colbase = wn * 64;
    const int pt0  = blockIdx.x * P_WG;

    float mst[4][4][4];    // master state (h / dh), fp32 [mt][nt][j] — static idx ONLY
    f32x4 acc[4][4];       // MFMA accumulators [mt][nt] — static idx ONLY

    if (tid < P_WG * 3) xyz[tid] = coords[pt0 * 3 + tid];

    auto stageW = [&](const float* __restrict__ src, float scale) {
        #pragma unroll
        for (int i = 0; i < 8; ++i) {
            const int g   = tid + (i << 8);        // chunk id 0..2047
            const int row = g >> 4, c = g & 15;
            const float4 v0 = *reinterpret_cast<const float4*>(src + (g << 3));
            const float4 v1 = *reinterpret_cast<const float4*>(src + (g << 3) + 4);
            uint4 w;
            w.x = bfbits(scale*v0.x) | (bfbits(scale*v0.y) << 16);
            w.y = bfbits(scale*v0.z) | (bfbits(scale*v0.w) << 16);
            w.z = bfbits(scale*v1.x) | (bfbits(scale*v1.y) << 16);
            w.w = bfbits(scale*v1.z) | (bfbits(scale*v1.w) << 16);
            *reinterpret_cast<uint4*>(W8 + (row << 8) + (((c ^ (row & 15)) << 4))) = w;
        }
    };

    stageW(res_w1, 1.0f);      // block 0 layer 1 (s=1)
    __syncthreads();

    // ---- first layer ----
    #pragma unroll
    for (int mt = 0; mt < 4; ++mt) {
        const int s_mt = 2*wm + (mt >> 1);     // wave-uniform; used in value selects only
        #pragma unroll
        for (int nt = 0; nt < 4; ++nt) {
            const int f = colbase + nt*16 + l15;
            const float w0 = first_w[f*3+0], w1 = first_w[f*3+1], w2 = first_w[f*3+2];
            const float fb = first_b[f];
            const float wk = (s_mt == 1) ? w0 : (s_mt == 2) ? w1 : w2;
            #pragma unroll
            for (int j = 0; j < 4; ++j) {
                const int p = (mt & 1)*16 + lq*4 + j;
                const float pre = OMEGA_C * (xyz[p*3]*w0 + xyz[p*3+1]*w1 + xyz[p*3+2]*w2 + fb);
                const float v = (s_mt == 0) ? __sinf(pre) : OMEGA_C * __cosf(pre) * wk;
                mst[mt][nt][j] = v;
                *reinterpret_cast<uint16_t*>(A8 + swz(rowbase + mt*16 + lq*4 + j, f))
                    = (uint16_t)bfbits(v);
            }
        }
    }
    __syncthreads();

    auto gemm = [&]() {
        #pragma unroll
        for (int mt = 0; mt < 4; ++mt)
            #pragma unroll
            for (int nt = 0; nt < 4; ++nt) acc[mt][nt] = f32x4{0.f,0.f,0.f,0.f};
        #pragma unroll
        for (int kk = 0; kk < 4; ++kk) {
            bf16x8 af[4];
            #pragma unroll
            for (int mt = 0; mt < 4; ++mt)
                af[mt] = *reinterpret_cast<const bf16x8*>(
                    A8 + swz(rowbase + mt*16 + l15, kk*32 + lq*8));
            #pragma unroll
            for (int nt = 0; nt < 4; ++nt) {
                const bf16x8 wf = *reinterpret_cast<const bf16x8*>(
                    W8 + swz(colbase + nt*16 + l15, kk*32 + lq*8));
                #pragma unroll
                for (int mt = 0; mt < 4; ++mt)
                    acc[mt][nt] = __builtin_amdgcn_mfma_f32_16x16x32_bf16(af[mt], wf, acc[mt][nt], 0, 0, 0);
            }
        }
    };

    #pragma unroll 1
    for (int b = 0; b < NBLK; ++b) {
        // ================= sub-layer 1: W = s*w1[b] =================
        gemm();
        if (wm == 0) {   // primal: compute sin/cos; publish cos (C8 not read by gemm);
                         // stage new A values in acc (A8 write deferred past barrier)
            #pragma unroll
            for (int mt = 0; mt < 2; ++mt)
                #pragma unroll
                for (int nt = 0; nt < 4; ++nt) {
                    const int f = colbase + nt*16 + l15;
                    const float ob = OMEGA_C * res_b1[b*FDIM + f];
                    #pragma unroll
                    for (int j = 0; j < 4; ++j) {
                        const int p = mt*16 + lq*4 + j;
                        const float pre = OMEGA_C * acc[mt][nt][j] + ob;
                        *reinterpret_cast<uint16_t*>(C8 + swz(p, f))
                            = (uint16_t)bfbits(OMEGA_C * __cosf(pre));
                        acc[mt][nt][j] = __sinf(pre);
                    }
                }
        }
        __syncthreads();   // all gemm A8/W8 reads done; C8 visible
        if (wm == 0) {     // write primal A rows
            #pragma unroll
            for (int mt = 0; mt < 2; ++mt)
                #pragma unroll
                for (int nt = 0; nt < 4; ++nt) {
                    const int f = colbase + nt*16 + l15;
                    #pragma unroll
                    for (int j = 0; j < 4; ++j)
                        *reinterpret_cast<uint16_t*>(A8 + swz(mt*16 + lq*4 + j, f))
                            = (uint16_t)bfbits(acc[mt][nt][j]);
                }
        }
        #pragma unroll
        for (int mt = 0; mt < 4; ++mt) {       // tangent rows (static mt, uniform guard)
            if (wm == 1 || mt >= 2) {
                #pragma unroll
                for (int nt = 0; nt < 4; ++nt) {
                    const int f = colbase + nt*16 + l15;
                    #pragma unroll
                    for (int j = 0; j < 4; ++j) {
                        const int p = (mt & 1)*16 + lq*4 + j;
                        const float cv = u16tof(*reinterpret_cast<const uint16_t*>(C8 + swz(p, f)));
                        const float v = cv * acc[mt][nt][j];
                        *reinterpret_cast<uint16_t*>(A8 + swz(rowbase + mt*16 + lq*4 + j, f))
                            = (uint16_t)bfbits(v);
                    }
                }
            }
        }
        stageW(res_w2 + b*FDIM*FDIM, 1.0f);
        __syncthreads();

        // ================= sub-layer 2: W = w2[b], residual =================
        gemm();
        if (wm == 0) {
            #pragma unroll
            for (int mt = 0; mt < 2; ++mt)
                #pragma unroll
                for (int nt = 0; nt < 4; ++nt) {
                    const int f = colbase + nt*16 + l15;
                    const float ob = OMEGA_C * res_b2[b*FDIM + f];
                    #pragma unroll
                    for (int j = 0; j < 4; ++j) {
                        const int p = mt*16 + lq*4 + j;
                        const float pre = OMEGA_C * acc[mt][nt][j] + ob;
                        *reinterpret_cast<uint16_t*>(C8 + swz(p, f))
                            = (uint16_t)bfbits(OMEGA_C * __cosf(pre));
                        mst[mt][nt][j] += __sinf(pre);
                        acc[mt][nt][j] = mst[mt][nt][j];
                    }
                }
        }
        __syncthreads();
        if (wm == 0) {
            #pragma unroll
            for (int mt = 0; mt < 2; ++mt)
                #pragma unroll
                for (int nt = 0; nt < 4; ++nt) {
                    const int f = colbase + nt*16 + l15;
                    #pragma unroll
                    for (int j = 0; j < 4; ++j)
                        *reinterpret_cast<uint16_t*>(A8 + swz(mt*16 + lq*4 + j, f))
                            = (uint16_t)bfbits(acc[mt][nt][j]);
                }
        }
        #pragma unroll
        for (int mt = 0; mt < 4; ++mt) {
            if (wm == 1 || mt >= 2) {
                #pragma unroll
                for (int nt = 0; nt < 4; ++nt) {
                    const int f = colbase + nt*16 + l15;
                    #pragma unroll
                    for (int j = 0; j < 4; ++j) {
                        const int p = (mt & 1)*16 + lq*4 + j;
                        const float cv = u16tof(*reinterpret_cast<const uint16_t*>(C8 + swz(p, f)));
                        mst[mt][nt][j] += cv * acc[mt][nt][j];
                        *reinterpret_cast<uint16_t*>(A8 + swz(rowbase + mt*16 + lq*4 + j, f))
                            = (uint16_t)bfbits(mst[mt][nt][j]);
                    }
                }
            }
        }
        if (b < NBLK-1) stageW(res_w1 + (b+1)*FDIM*FDIM, 0.5f);   // s=0.5 folded
        __syncthreads();
    }

    // ---- final: out[:,c] = signed combos of dh_k . final_w[row] ----
    // k=0: wr={0,3,2} sg={+,-,+}; k=1: wr={3,0,1} sg={+,+,-}; k=2: wr={2,1,0} sg={-,+,+}
    #pragma unroll
    for (int mt = 0; mt < 4; ++mt) {
        if (wm == 1 || mt >= 2) {
            const int k = 2*wm + (mt >> 1) - 1;   // wave-uniform; LDS/select use only
            #pragma unroll
            for (int c = 0; c < 3; ++c) {
                int wr; float sg;
                if (c == 0)      { wr = (k==0)?0:(k==1)?3:2; sg = (k==2)?-1.f:1.f; }
                else if (c == 1) { wr = (k==0)?3:(k==1)?0:1; sg = (k==0)?-1.f:1.f; }
                else             { wr = (k==0)?2:(k==1)?1:0; sg = (k==1)?-1.f:1.f; }
                float fwv[4];
                #pragma unroll
                for (int nt = 0; nt < 4; ++nt)
                    fwv[nt] = final_w[wr*FDIM + colbase + nt*16 + l15];
                #pragma unroll
                for (int j = 0; j < 4; ++j) {
                    float part = 0.0f;
                    #pragma unroll
                    for (int nt = 0; nt < 4; ++nt) part += mst[mt][nt][j] * fwv[nt];
                    part += __shfl_xor(part, 1);
                    part += __shfl_xor(part, 2);
                    part += __shfl_xor(part, 4);
                    part += __shfl_xor(part, 8);
                    if (l15 == 0) outp[k][wn][(mt & 1)*16 + lq*4 + j][c] = sg * part;
                }
            }
        }
    }
    __syncthreads();

    if (tid < P_WG * 3) {
        const int p = tid / 3, c = tid % 3;
        out[(pt0 + p)*3 + c] = outp[0][0][p][c] + outp[0][1][p][c]
                             + outp[1][0][p][c] + outp[1][1][p][c]
                             + outp[2][0][p][c] + outp[2][1][p][c];
    }
}

extern "C" void kernel_launch(void* const* d_in, const int* in_sizes, int n_in,
                              void* d_out, int out_size, void* d_ws, size_t ws_size,
                              hipStream_t stream) {
    const float* coords  = (const float*)d_in[0];
    const float* first_w = (const float*)d_in[1];
    const float* first_b = (const float*)d_in[2];
    const float* res_w1  = (const float*)d_in[3];
    const float* res_b1  = (const float*)d_in[4];
    const float* res_w2  = (const float*)d_in[5];
    const float* res_b2  = (const float*)d_in[6];
    const float* final_w = (const float*)d_in[7];
    // final_b (d_in[8]) does not influence the Jacobian -> unused.

    dim3 grid(NPTS / P_WG);   // 4096 workgroups
    fsrn_kernel<<<grid, NTHR, 0, stream>>>(coords, first_w, first_b,
                                           res_w1, res_b1, res_w2, res_b2,
                                           final_w, (float*)d_out);
}